// Round 1
// 459.665 us; speedup vs baseline: 1.1296x; 1.1296x over previous
//
#include <hip/hip_runtime.h>

// Problem constants (from reference): z (64,128,64,64) f32, emb (256,128) f32
#define K_EMB   256
#define C_DIM   128
#define HW      4096            // 64*64
#define NPOS    262144          // 64*HW
#define Q_ELEMS 33554432        // 64*128*64*64
#define IDX_OFF Q_ELEMS         // idx chunk offset in d_out (floats)
#define LOSS_OFF (Q_ELEMS + NPOS)

#define TK 64                   // codes per k-chunk (accumulators per lane)

// ws layout (floats): [0,256) enorm, [256] loss accumulator, [512, 512+32768) embT (c*256+k)
#define WS_ENORM 0
#define WS_ACC   256
#define WS_EMBT  512
#define WS_NEED_FULL  ((WS_EMBT + C_DIM * K_EMB) * 4)

// ---------------------------------------------------------------------------
// Kernel 0: per-code squared norms, emb transpose (c-major), zero loss accum.
// ---------------------------------------------------------------------------
__global__ __launch_bounds__(K_EMB) void vq_prep(const float* __restrict__ emb,
                                                 float* __restrict__ ws,
                                                 int use_embT) {
    int k = threadIdx.x;  // 256 threads, 1 block
    float s = 0.f;
    #pragma unroll 8
    for (int c = 0; c < C_DIM; ++c) {
        float e = emb[k * C_DIM + c];
        s = fmaf(e, e, s);
        if (use_embT) ws[WS_EMBT + c * K_EMB + k] = e;
    }
    ws[WS_ENORM + k] = s;
    if (k == 0) ws[WS_ACC] = 0.f;
}

// ---------------------------------------------------------------------------
// Kernel 1: register-blocked VALU GEMM + argmin.
//
// R5 (this round): counters showed VALUBusy 44% / HBM 29% / occupancy grid-
// capped at 4 blocks/CU -- latency-bound, not pipe-bound. TK 32->64 halves
// the z re-stream count (8 GEMM passes -> 4) and doubles FMAs per in-flight
// load; znorm is fused into chunk 0 (removes one full z pass); q/idx stores
// are non-temporal so the 134 MB write stream stops evicting z from L3
// (z+q = 268 MB > 256 MB L3 was the FETCH_SIZE=655MB culprit).
//
// Numerics: per-(pos,k) dot is still ONE serial ascending-c fp32 fma chain;
// znorm is the same serial chain (fusing changes when, not what); d =
// (znorm - 2*acc) + enorm[k]; strict < ascending-k tiebreak -- bit-identical
// to the R1/R4 kernel that passed with absmax 0. NT stores don't change
// values.
// ---------------------------------------------------------------------------
template <int UT, int ZN>
__device__ __forceinline__ void vq_chunk(const float* __restrict__ zp,
                                         const float* __restrict__ embT,
                                         const float* __restrict__ emb,
                                         int kc, float* __restrict__ acc,
                                         float& znorm) {
    #pragma unroll
    for (int j = 0; j < TK; ++j) acc[j] = 0.f;

    #pragma unroll 2
    for (int c = 0; c < C_DIM; ++c) {
        float zc = zp[(size_t)c * HW];            // per-lane vector load
        if (ZN) znorm = fmaf(zc, zc, znorm);      // same serial chain as before
        if (UT) {
            const float* __restrict__ ep = embT + c * K_EMB + kc;  // wave-uniform
            #pragma unroll
            for (int j = 0; j < TK; ++j)
                acc[j] = fmaf(zc, ep[j], acc[j]); // VGPR x SGPR fmac
        } else {
            #pragma unroll
            for (int j = 0; j < TK; ++j)
                acc[j] = fmaf(zc, emb[(kc + j) * C_DIM + c], acc[j]);
        }
    }
}

template <int UT>
__global__ __launch_bounds__(256, 4) void vq_main(const float* __restrict__ z,
                                                  const float* __restrict__ emb,
                                                  const float* __restrict__ ws,
                                                  float* __restrict__ out,
                                                  float* __restrict__ loss_acc) {
    const int pos = blockIdx.x * 256 + threadIdx.x;   // flat (b, h, w)
    const int b   = pos >> 12;                        // / 4096
    const int hw  = pos & 4095;

    const float* __restrict__ zp    = z + (size_t)b * (C_DIM * HW) + hw;
    const float* __restrict__ embT  = ws + WS_EMBT;
    const float* __restrict__ enorm = ws + WS_ENORM;

    float znorm = 0.f;
    float best  = 3.402823466e38f;
    int   bidx  = 0;
    float acc[TK];

    // chunk 0: znorm fused into the same z stream (one fewer full pass).
    vq_chunk<UT, 1>(zp, embT, emb, 0, acc, znorm);
    #pragma unroll
    for (int j = 0; j < TK; ++j) {
        float d = (znorm - 2.0f * acc[j]) + enorm[j];
        if (d < best) { best = d; bidx = j; }         // strict < = first-min
    }

    for (int kc = TK; kc < K_EMB; kc += TK) {
        vq_chunk<UT, 0>(zp, embT, emb, kc, acc, znorm);
        #pragma unroll
        for (int j = 0; j < TK; ++j) {
            float d = (znorm - 2.0f * acc[j]) + enorm[kc + j];
            if (d < best) { best = d; bidx = kc + j; }
        }
    }

    __builtin_nontemporal_store((float)bidx, &out[IDX_OFF + pos]);

    // Epilogue: quantized_ste = z + (e - z), accumulate (e - z)^2.
    // z re-read is L3-hot (just streamed in the last chunk); q write is NT
    // so it streams past L3 instead of evicting z.
    float lsum = 0.f;
    float* qp = out + (size_t)b * (C_DIM * HW) + hw;
    #pragma unroll 4
    for (int c = 0; c < C_DIM; ++c) {
        float zc = zp[(size_t)c * HW];
        float e  = UT ? embT[c * K_EMB + bidx] : emb[bidx * C_DIM + c];
        float dq = e - zc;
        lsum = fmaf(dq, dq, lsum);
        __builtin_nontemporal_store(zc + dq, &qp[(size_t)c * HW]);
    }

    // Wave-level reduction, one atomic per wave.
    #pragma unroll
    for (int off = 32; off > 0; off >>= 1)
        lsum += __shfl_down(lsum, off, 64);
    if ((threadIdx.x & 63) == 0) atomicAdd(loss_acc, lsum);
}

// ---------------------------------------------------------------------------
// Kernel 2: finalize the two scalar losses.
// ---------------------------------------------------------------------------
__global__ void vq_finalize(const float* __restrict__ loss_acc,
                            float* __restrict__ out_losses) {
    float S = loss_acc[0];
    float mean = S / (float)Q_ELEMS;
    out_losses[0] = 0.25f * mean;  // commitment_loss
    out_losses[1] = mean;          // codebook_loss
}

extern "C" void kernel_launch(void* const* d_in, const int* in_sizes, int n_in,
                              void* d_out, int out_size, void* d_ws, size_t ws_size,
                              hipStream_t stream) {
    const float* z   = (const float*)d_in[0];
    const float* emb = (const float*)d_in[1];
    float* out = (float*)d_out;
    float* ws  = (float*)d_ws;

    int use_embT = (ws_size >= (size_t)WS_NEED_FULL) ? 1 : 0;

    vq_prep<<<1, K_EMB, 0, stream>>>(emb, ws, use_embT);
    if (use_embT)
        vq_main<1><<<NPOS / 256, 256, 0, stream>>>(z, emb, ws, out, ws + WS_ACC);
    else
        vq_main<0><<<NPOS / 256, 256, 0, stream>>>(z, emb, ws, out, ws + WS_ACC);
    vq_finalize<<<1, 1, 0, stream>>>(ws + WS_ACC, out + LOSS_OFF);
}